// Round 1
// baseline (1590.671 us; speedup 1.0000x reference)
//
#include <hip/hip_runtime.h>

// ---------------------------------------------------------------------------
// Transformer (B=2, N=2048, D=1024, H=16, DH=64, DEPTH=4, FF=4, GEGLU, causal)
// Strategy: fp32 residual stream in d_out; bf16 MFMA (16x16x32) for all GEMMs
// and attention; weights transposed+cast to bf16 B^T layout once per launch.
// ---------------------------------------------------------------------------

typedef float f32x4 __attribute__((ext_vector_type(4)));
typedef __bf16 bf16x8 __attribute__((ext_vector_type(8)));
typedef unsigned short u16;
typedef unsigned int u32;

#define ATT_SCALE 0.125f   // DH^-0.5
#define LN_EPS 1e-3f

__device__ __forceinline__ u16 f2bf(float f) {
  u32 u = __float_as_uint(f);
  u += 0x7fffu + ((u >> 16) & 1u);   // round-to-nearest-even
  return (u16)(u >> 16);
}

// async global->LDS, 16B per lane; lds base must be wave-uniform (HW adds lane*16)
__device__ __forceinline__ void stage16(void* lds_wave_base, const void* gsrc) {
  __builtin_amdgcn_global_load_lds((__attribute__((address_space(1))) void*)gsrc,
                                   (__attribute__((address_space(3))) void*)lds_wave_base,
                                   16, 0, 0);
}

// ---------------------------------------------------------------------------
// Weight transpose + cast: W f32 [L][K][N] -> WT bf16 [L][N][K].
// permMode=1 (W1): output row permuted so 16 a-cols and 16 gate-cols alternate,
// letting the FF1 epilogue pair acc n-tiles (nt even = a, nt odd = gate).
// ---------------------------------------------------------------------------
__global__ void wtrans_kernel(const float* __restrict__ W, u16* __restrict__ WT,
                              int K, int N, int permMode) {
  __shared__ float tile[32][33];
  const int n0 = blockIdx.x * 32, k0 = blockIdx.y * 32;
  const float* Wl = W + (size_t)blockIdx.z * K * N;
  u16* WTl = WT + (size_t)blockIdx.z * K * N;
  const int tx = threadIdx.x, ty = threadIdx.y;
#pragma unroll
  for (int i = 0; i < 4; ++i)
    tile[ty + i * 8][tx] = Wl[(size_t)(k0 + ty + i * 8) * N + n0 + tx];
  __syncthreads();
#pragma unroll
  for (int i = 0; i < 4; ++i) {
    const int n = n0 + ty + i * 8;
    int orow;
    if (permMode) {
      orow = (n < 4096) ? (((n >> 4) << 5) + (n & 15))
                        : ((((n - 4096) >> 4) << 5) + 16 + (n & 15));
    } else {
      orow = n;
    }
    WTl[(size_t)orow * K + k0 + tx] = f2bf(tile[tx][ty + i * 8]);
  }
}

// V part of qkv -> per-(b,h) transposed V^T [bh][64 d][2048 tok] (bf16)
__global__ void vtrans_kernel(const u16* __restrict__ qkv, u16* __restrict__ Vt) {
  __shared__ u16 tile[32][33];
  const int t0 = blockIdx.x * 32, d0 = blockIdx.y * 32, bh = blockIdx.z;
  const int b = bh >> 4, h = bh & 15;
  const int tx = threadIdx.x, ty = threadIdx.y;
#pragma unroll
  for (int i = 0; i < 4; ++i)
    tile[ty + i * 8][tx] =
        qkv[((size_t)(b * 2048 + t0 + ty + i * 8)) * 3072 + 2048 + h * 64 + d0 + tx];
  __syncthreads();
#pragma unroll
  for (int i = 0; i < 4; ++i)
    Vt[((size_t)bh * 64 + d0 + ty + i * 8) * 2048 + t0 + tx] = tile[tx][ty + i * 8];
}

// ---------------------------------------------------------------------------
// LayerNorm: x f32 [4096][1024] -> y bf16, per-row mean/var, fp32 stats
// ---------------------------------------------------------------------------
__global__ __launch_bounds__(256, 4)
void ln_kernel(const float* __restrict__ x, const float* __restrict__ g,
               const float* __restrict__ b, u16* __restrict__ y) {
  const int row = blockIdx.x, tid = threadIdx.x;
  const float4 v = ((const float4*)(x + (size_t)row * 1024))[tid];
  float s = v.x + v.y + v.z + v.w;
  float s2 = v.x * v.x + v.y * v.y + v.z * v.z + v.w * v.w;
#pragma unroll
  for (int off = 32; off > 0; off >>= 1) {
    s += __shfl_down(s, off);
    s2 += __shfl_down(s2, off);
  }
  __shared__ float ps[8];
  __shared__ float stats[2];
  const int wv = tid >> 6, lane = tid & 63;
  if (lane == 0) { ps[wv] = s; ps[wv + 4] = s2; }
  __syncthreads();
  if (tid == 0) {
    const float S = ps[0] + ps[1] + ps[2] + ps[3];
    const float S2 = ps[4] + ps[5] + ps[6] + ps[7];
    const float mu = S * (1.0f / 1024.0f);
    const float var = S2 * (1.0f / 1024.0f) - mu * mu;
    stats[0] = mu;
    stats[1] = rsqrtf(var + LN_EPS);
  }
  __syncthreads();
  const float mu = stats[0], rs = stats[1];
  const float4 gg = ((const float4*)g)[tid];
  const float4 bb = ((const float4*)b)[tid];
  ushort4 ov;
  ov.x = f2bf((v.x - mu) * rs * gg.x + bb.x);
  ov.y = f2bf((v.y - mu) * rs * gg.y + bb.y);
  ov.z = f2bf((v.z - mu) * rs * gg.z + bb.z);
  ov.w = f2bf((v.w - mu) * rs * gg.w + bb.w);
  ((ushort4*)(y + (size_t)row * 1024))[tid] = ov;
}

// ---------------------------------------------------------------------------
// m97-style GEMM: C[M,N] = A[M,K] * B^T[N,K], bf16 in, fp32 acc.
// 128x128 tile, BK=32, 256 thr = 4 waves (2x2 of 64x64), 16x16x32 MFMA.
// EPI 0: out bf16 = acc               (QKV)
// EPI 1: resid f32 += acc + bias[n]   (Wout, FF2 residual add)
// EPI 2: GEGLU: pair nt (even=a, odd=gate), out bf16 [M][4096]  (FF1)
// ---------------------------------------------------------------------------
template <int EPI>
__global__ __launch_bounds__(256, 2)
void gemm_bt(const u16* __restrict__ A, const u16* __restrict__ B,
             float* __restrict__ resid, const float* __restrict__ bias,
             u16* __restrict__ out, int M, int N, int K) {
  __shared__ __align__(16) u16 As[128 * 32];
  __shared__ __align__(16) u16 Bs[128 * 32];
  const int tid = threadIdx.x;
  const int wv = tid >> 6, lane = tid & 63;
  const int lr = lane & 15, lg = lane >> 4;
  const int m0 = blockIdx.y * 128, n0 = blockIdx.x * 128;
  const int wm = (wv & 1) * 64, wn = (wv >> 1) * 64;

  f32x4 acc[4][4] = {};

  for (int k0 = 0; k0 < K; k0 += 32) {
    __syncthreads();
#pragma unroll
    for (int i = 0; i < 2; ++i) {
      const int cb = i * 256 + wv * 64;   // wave-uniform chunk base
      const int c = cb + lane;
      const int row = c >> 2, ko = (c & 3) * 8;   // 4 x 16B chunks per 32-elem row
      stage16((char*)As + cb * 16, A + (size_t)(m0 + row) * K + k0 + ko);
      stage16((char*)Bs + cb * 16, B + (size_t)(n0 + row) * K + k0 + ko);
    }
    __syncthreads();   // drains vmcnt before barrier

    bf16x8 af[4], bf[4];
#pragma unroll
    for (int t = 0; t < 4; ++t) {
      af[t] = *(const bf16x8*)(As + (wm + t * 16 + lr) * 32 + lg * 8);
      bf[t] = *(const bf16x8*)(Bs + (wn + t * 16 + lr) * 32 + lg * 8);
    }
#pragma unroll
    for (int mt = 0; mt < 4; ++mt)
#pragma unroll
      for (int nt = 0; nt < 4; ++nt)
        acc[mt][nt] =
            __builtin_amdgcn_mfma_f32_16x16x32_bf16(af[mt], bf[nt], acc[mt][nt], 0, 0, 0);
  }

  // C/D layout: m = wm + mt*16 + lg*4 + r ; n = wn + nt*16 + lr
  if (EPI == 0) {
#pragma unroll
    for (int mt = 0; mt < 4; ++mt)
#pragma unroll
      for (int nt = 0; nt < 4; ++nt) {
        const int n = n0 + wn + nt * 16 + lr;
#pragma unroll
        for (int r = 0; r < 4; ++r) {
          const int m = m0 + wm + mt * 16 + lg * 4 + r;
          out[(size_t)m * N + n] = f2bf(acc[mt][nt][r]);
        }
      }
  } else if (EPI == 1) {
    float bs[4];
#pragma unroll
    for (int nt = 0; nt < 4; ++nt) bs[nt] = bias[n0 + wn + nt * 16 + lr];
#pragma unroll
    for (int mt = 0; mt < 4; ++mt)
#pragma unroll
      for (int nt = 0; nt < 4; ++nt) {
        const int n = n0 + wn + nt * 16 + lr;
#pragma unroll
        for (int r = 0; r < 4; ++r) {
          const int m = m0 + wm + mt * 16 + lg * 4 + r;
          resid[(size_t)m * N + n] += acc[mt][nt][r] + bs[nt];
        }
      }
  } else {
#pragma unroll
    for (int pt = 0; pt < 2; ++pt) {
      const int colA = (((n0 + wn) >> 5) + pt) * 16 + lr;  // GEGLU output col / b1 a-index
      const float ba = bias[colA];
      const float bg = bias[4096 + colA];
#pragma unroll
      for (int mt = 0; mt < 4; ++mt)
#pragma unroll
        for (int r = 0; r < 4; ++r) {
          const int m = m0 + wm + mt * 16 + lg * 4 + r;
          const float a = acc[mt][2 * pt][r] + ba;
          const float g = acc[mt][2 * pt + 1][r] + bg;
          const float gl = 0.5f * g * (1.0f + erff(g * 0.70710678118654752f));
          out[(size_t)m * 4096 + colA] = f2bf(a * gl);
        }
    }
  }
}

// ---------------------------------------------------------------------------
// Causal flash attention. Block = (qb, b*16+h), 256 thr = 4 waves.
// Q tile 64x64 (wave owns 16 q rows); K/V tiles 64 wide, online softmax fp32.
// LDS rows are 128B -> XOR swizzle (chunk ^= row&7) on both the pre-swizzled
// global_load_lds source and the ds_read_b128 side (involution).
// ---------------------------------------------------------------------------
__global__ __launch_bounds__(256, 2)
void attn_kernel(const u16* __restrict__ qkv, const u16* __restrict__ Vt,
                 u16* __restrict__ attnout) {
  __shared__ __align__(16) u16 Qs[64 * 64];
  __shared__ __align__(16) u16 Ks[64 * 64];
  __shared__ __align__(16) u16 Vs[64 * 64];   // V^T tile: [d][kt]
  __shared__ __align__(16) u16 Ps[4 * 16 * 64];

  const int tid = threadIdx.x;
  const int wv = tid >> 6, lane = tid & 63;
  const int lr = lane & 15, lg = lane >> 4;
  const int qb = (int)gridDim.x - 1 - (int)blockIdx.x;   // heavy blocks first
  const int bh = blockIdx.y;
  const int b = bh >> 4, h = bh & 15;
  const size_t tokbase = (size_t)b * 2048;

#pragma unroll
  for (int i = 0; i < 2; ++i) {
    const int cb = i * 256 + wv * 64;
    const int c = cb + lane;
    const int row = c >> 3;                  // 8 x 16B chunks per 64-elem row
    const int jl = (c & 7) ^ (row & 7);      // logical chunk for this phys slot
    stage16((char*)Qs + cb * 16,
            qkv + ((tokbase + qb * 64 + row) * 3072 + h * 64 + jl * 8));
  }
  __syncthreads();

  bf16x8 qf[2];
  {
    const int row = wv * 16 + lr;
#pragma unroll
    for (int ks = 0; ks < 2; ++ks) {
      const int jp = (ks * 4 + lg) ^ (row & 7);
      qf[ks] = *(const bf16x8*)(Qs + row * 64 + jp * 8);
    }
  }

  f32x4 o[4] = {};
  float mreg[4] = {-1e30f, -1e30f, -1e30f, -1e30f};
  float lreg[4] = {0.f, 0.f, 0.f, 0.f};

  for (int kt = 0; kt <= qb; ++kt) {
    __syncthreads();
#pragma unroll
    for (int i = 0; i < 2; ++i) {
      const int cb = i * 256 + wv * 64;
      const int c = cb + lane;
      const int row = c >> 3;
      const int jl = (c & 7) ^ (row & 7);
      stage16((char*)Ks + cb * 16,
              qkv + ((tokbase + kt * 64 + row) * 3072 + 1024 + h * 64 + jl * 8));
      stage16((char*)Vs + cb * 16,
              Vt + (((size_t)bh * 64 + row) * 2048 + kt * 64 + jl * 8));
    }
    __syncthreads();

    // S = Q K^T  (A = Q rows, B^T = K rows, k = d)
    f32x4 s[4] = {};
#pragma unroll
    for (int ks = 0; ks < 2; ++ks) {
#pragma unroll
      for (int nt = 0; nt < 4; ++nt) {
        const int row = nt * 16 + lr;
        const int jp = (ks * 4 + lg) ^ (row & 7);
        const bf16x8 kf = *(const bf16x8*)(Ks + row * 64 + jp * 8);
        s[nt] = __builtin_amdgcn_mfma_f32_16x16x32_bf16(qf[ks], kf, s[nt], 0, 0, 0);
      }
    }

    // online softmax (row = lg*4 + r across 16-lane group)
#pragma unroll
    for (int r = 0; r < 4; ++r) {
      const int rloc = lg * 4 + r;
      const int qg = qb * 64 + wv * 16 + rloc;
      float mx = -1e30f;
#pragma unroll
      for (int nt = 0; nt < 4; ++nt) {
        float v = s[nt][r] * ATT_SCALE;
        const int kg = kt * 64 + nt * 16 + lr;
        v = (kg <= qg) ? v : -1e30f;   // causal mask
        s[nt][r] = v;
        mx = fmaxf(mx, v);
      }
#pragma unroll
      for (int off = 1; off < 16; off <<= 1) mx = fmaxf(mx, __shfl_xor(mx, off));
      const float mn = fmaxf(mreg[r], mx);
      const float alpha = __expf(mreg[r] - mn);
      mreg[r] = mn;
      float rsum = 0.f;
#pragma unroll
      for (int nt = 0; nt < 4; ++nt) {
        const float p = __expf(s[nt][r] - mn);
        rsum += p;
        const int col2 = (nt * 16 + lr) * 2;
        *(u16*)((char*)Ps + wv * 2048 + rloc * 128 + (col2 ^ ((rloc & 7) << 4))) = f2bf(p);
      }
#pragma unroll
      for (int off = 1; off < 16; off <<= 1) rsum += __shfl_xor(rsum, off);
      lreg[r] = lreg[r] * alpha + rsum;
#pragma unroll
      for (int dt = 0; dt < 4; ++dt) o[dt][r] *= alpha;
    }

    __syncthreads();   // cheap insurance: drain P writes before P reads

    // O += P V   (A = P rows (q), k = kt; B^T = V^T rows (d))
#pragma unroll
    for (int ks = 0; ks < 2; ++ks) {
      const int jpp = (ks * 4 + lg) ^ (lr & 7);
      const bf16x8 pf =
          *(const bf16x8*)((const u16*)((const char*)Ps + wv * 2048) + lr * 64 + jpp * 8);
#pragma unroll
      for (int dt = 0; dt < 4; ++dt) {
        const int vrow = dt * 16 + lr;
        const int vjp = (ks * 4 + lg) ^ (vrow & 7);
        const bf16x8 vf = *(const bf16x8*)(Vs + vrow * 64 + vjp * 8);
        o[dt] = __builtin_amdgcn_mfma_f32_16x16x32_bf16(pf, vf, o[dt], 0, 0, 0);
      }
    }
  }

#pragma unroll
  for (int dt = 0; dt < 4; ++dt)
#pragma unroll
    for (int r = 0; r < 4; ++r) {
      const float v = o[dt][r] / lreg[r];
      const size_t tok = tokbase + qb * 64 + wv * 16 + lg * 4 + r;
      attnout[tok * 1024 + h * 64 + dt * 16 + lr] = f2bf(v);
    }
}

// ---------------------------------------------------------------------------
extern "C" void kernel_launch(void* const* d_in, const int* in_sizes, int n_in,
                              void* d_out, int out_size, void* d_ws, size_t ws_size,
                              hipStream_t stream) {
  (void)in_sizes; (void)n_in; (void)ws_size;
  const float* x_in  = (const float*)d_in[0];
  // d_in[1] = mask: all-true in this problem; padding mask is a no-op.
  const float* ln1_g = (const float*)d_in[2];
  const float* ln1_b = (const float*)d_in[3];
  const float* Wqkv  = (const float*)d_in[4];
  const float* Wout  = (const float*)d_in[5];
  const float* bout  = (const float*)d_in[6];
  const float* ln2_g = (const float*)d_in[7];
  const float* ln2_b = (const float*)d_in[8];
  const float* W1    = (const float*)d_in[9];
  const float* b1    = (const float*)d_in[10];
  const float* W2    = (const float*)d_in[11];
  const float* b2    = (const float*)d_in[12];
  float* x = (float*)d_out;   // residual stream lives in d_out

  char* ws = (char*)d_ws;
  size_t off = 0;
  auto alloc = [&](size_t bytes) -> void* {
    void* p = ws + off;
    off += (bytes + 255) & ~(size_t)255;
    return p;
  };
  u16* WqkvT = (u16*)alloc(4ull * 3072 * 1024 * 2);
  u16* WoutT = (u16*)alloc(4ull * 1024 * 1024 * 2);
  u16* W1T   = (u16*)alloc(4ull * 8192 * 1024 * 2);
  u16* W2T   = (u16*)alloc(4ull * 1024 * 4096 * 2);
  u16* y     = (u16*)alloc(4096ull * 1024 * 2);
  u16* qkvb  = (u16*)alloc(4096ull * 3072 * 2);
  u16* Vt    = (u16*)alloc(32ull * 64 * 2048 * 2);
  u16* attn  = (u16*)alloc(4096ull * 1024 * 2);
  u16* ff    = (u16*)alloc(4096ull * 4096 * 2);

  hipMemcpyAsync(x, x_in, (size_t)out_size * 4, hipMemcpyDeviceToDevice, stream);

  const dim3 tb(32, 8);
  wtrans_kernel<<<dim3(3072 / 32, 1024 / 32, 4), tb, 0, stream>>>(Wqkv, WqkvT, 1024, 3072, 0);
  wtrans_kernel<<<dim3(1024 / 32, 1024 / 32, 4), tb, 0, stream>>>(Wout, WoutT, 1024, 1024, 0);
  wtrans_kernel<<<dim3(8192 / 32, 1024 / 32, 4), tb, 0, stream>>>(W1, W1T, 1024, 8192, 1);
  wtrans_kernel<<<dim3(1024 / 32, 4096 / 32, 4), tb, 0, stream>>>(W2, W2T, 4096, 1024, 0);

  for (int l = 0; l < 4; ++l) {
    ln_kernel<<<4096, 256, 0, stream>>>(x, ln1_g + l * 1024, ln1_b + l * 1024, y);
    gemm_bt<0><<<dim3(3072 / 128, 4096 / 128), 256, 0, stream>>>(
        y, WqkvT + (size_t)l * 3072 * 1024, nullptr, nullptr, qkvb, 4096, 3072, 1024);
    vtrans_kernel<<<dim3(64, 2, 32), tb, 0, stream>>>(qkvb, Vt);
    attn_kernel<<<dim3(32, 32), 256, 0, stream>>>(qkvb, Vt, attn);
    gemm_bt<1><<<dim3(1024 / 128, 4096 / 128), 256, 0, stream>>>(
        attn, WoutT + (size_t)l * 1024 * 1024, x, bout + l * 1024, nullptr, 4096, 1024, 1024);
    ln_kernel<<<4096, 256, 0, stream>>>(x, ln2_g + l * 1024, ln2_b + l * 1024, y);
    gemm_bt<2><<<dim3(8192 / 128, 4096 / 128), 256, 0, stream>>>(
        y, W1T + (size_t)l * 8192 * 1024, nullptr, b1 + l * 8192, ff, 4096, 8192, 1024);
    gemm_bt<1><<<dim3(1024 / 128, 4096 / 128), 256, 0, stream>>>(
        ff, W2T + (size_t)l * 1024 * 4096, x, b2 + l * 1024, nullptr, 4096, 1024, 4096);
  }
}